// Round 4
// baseline (126.855 us; speedup 1.0000x reference)
//
#include <hip/hip_runtime.h>

// Chamfer loss, B=8, N=M=8192, D=3, fp32.
// Points transformed to T = (-x, -y, -z, 0.5*||x||^2).
// For owned p (VGPRs: px=-p.x,..., pw=0.5||p||^2) and scan s (SGPRs):
//   v = fma(px,-sx, fma(py,-sy, fma(pz,-sz, sw))) = 0.5||s||^2 - p.s
//   min over s, then d_min = 2*(min + pw) = min_s ||p-s||^2.
// Scan tile is wave-uniform -> scalar loads (SGPR operands), no LDS.

#define U 8
#define TSTEP 8
#define SPLIT 8
#define NPTS 8192      // N == M
#define BATCH 8
#define PER_DIR (BATCH * NPTS)  // 65536 owned slots per direction

__global__ __launch_bounds__(256) void transform_kernel(
    const float* __restrict__ preds, const float* __restrict__ gts,
    float4* __restrict__ Tp, float4* __restrict__ Tg) {
  int i = blockIdx.x * blockDim.x + threadIdx.x;  // 0 .. 2*PER_DIR-1
  const float* src;
  float4* dst;
  int j;
  if (i < PER_DIR) {
    src = preds; dst = Tp; j = i;
  } else {
    src = gts; dst = Tg; j = i - PER_DIR;
  }
  float x = src[3 * j + 0], y = src[3 * j + 1], z = src[3 * j + 2];
  dst[j] = make_float4(-x, -y, -z, 0.5f * fmaf(x, x, fmaf(y, y, z * z)));
}

// grid = 2 * BATCH * (NPTS/(256*U)) * SPLIT = 512 blocks (2 per CU)
__global__ __launch_bounds__(256) void chamfer_min_kernel(
    const float4* __restrict__ Tg, const float4* __restrict__ Tp,
    float* __restrict__ partP, float* __restrict__ partG) {
  const int tid = threadIdx.x;
  const int ownPerBlock = 256 * U;              // 2048
  const int ownChunks = NPTS / ownPerBlock;     // 4
  const int blocksPerDir = BATCH * ownChunks * SPLIT;  // 256

  int id = blockIdx.x;
  const int dir = id / blocksPerDir;
  id %= blocksPerDir;
  const int b = id / (ownChunks * SPLIT);
  const int r = id % (ownChunks * SPLIT);
  const int oc = r / SPLIT;
  const int sp = r % SPLIT;
  const int scanLen = NPTS / SPLIT;             // 1024

  const float4* own = (dir == 0 ? Tp : Tg) + (size_t)b * NPTS + oc * ownPerBlock;
  const float4* scan = (dir == 0 ? Tg : Tp) + (size_t)b * NPTS + sp * scanLen;
  float* outp = (dir == 0 ? partP : partG) + (size_t)sp * PER_DIR +
                (size_t)b * NPTS + oc * ownPerBlock;

  float px[U], py[U], pz[U], pw[U], m[U];
#pragma unroll
  for (int k = 0; k < U; ++k) {
    float4 t = own[k * 256 + tid];
    px[k] = t.x;   // = -p.x
    py[k] = t.y;
    pz[k] = t.z;
    pw[k] = t.w;   // = 0.5*||p||^2
    m[k] = 3.0e38f;
  }

  for (int t0 = 0; t0 < scanLen; t0 += TSTEP) {
    // wave-uniform scan chunk -> scalar loads (SGPRs)
    float sx[TSTEP], sy[TSTEP], sz[TSTEP], sw[TSTEP];
#pragma unroll
    for (int j = 0; j < TSTEP; ++j) {
      float4 s = scan[t0 + j];
      sx[j] = s.x; sy[j] = s.y; sz[j] = s.z; sw[j] = s.w;
    }
#pragma unroll
    for (int j = 0; j < TSTEP; j += 2) {
#pragma unroll
      for (int k = 0; k < U; ++k) {
        float v0 = fmaf(px[k], -sx[j],
                        fmaf(py[k], -sy[j], fmaf(pz[k], -sz[j], sw[j])));
        float v1 = fmaf(px[k], -sx[j + 1],
                        fmaf(py[k], -sy[j + 1],
                             fmaf(pz[k], -sz[j + 1], sw[j + 1])));
        m[k] = fminf(fminf(m[k], v0), v1);  // hope: v_min3_f32
      }
    }
  }

#pragma unroll
  for (int k = 0; k < U; ++k) {
    outp[k * 256 + tid] = 2.0f * (m[k] + pw[k]);
  }
}

// Stage A: min over SPLIT partials per owned slot, sum per block.
// partial layout: [2][SPLIT][PER_DIR]. 128 blocks x 256 threads.
__global__ __launch_bounds__(256) void reduce_a_kernel(
    const float* __restrict__ partial, float* __restrict__ blockSums) {
  const int nSlots = 2 * PER_DIR;  // 131072
  const int gid = blockIdx.x * 256 + threadIdx.x;
  const int stride = 128 * 256;
  float s = 0.0f;
  for (int sl = gid; sl < nSlots; sl += stride) {
    const int dir = sl >> 16;          // PER_DIR == 65536
    const int idx = sl & (PER_DIR - 1);
    const float* base = partial + (size_t)dir * SPLIT * PER_DIR + idx;
    float mn = base[0];
#pragma unroll
    for (int sp = 1; sp < SPLIT; ++sp) mn = fminf(mn, base[(size_t)sp * PER_DIR]);
    s += mn;
  }
#pragma unroll
  for (int off = 32; off > 0; off >>= 1) s += __shfl_down(s, off, 64);
  __shared__ float part[4];
  int wid = threadIdx.x >> 6, lane = threadIdx.x & 63;
  if (lane == 0) part[wid] = s;
  __syncthreads();
  if (threadIdx.x == 0) {
    blockSums[blockIdx.x] = part[0] + part[1] + part[2] + part[3];
  }
}

__global__ __launch_bounds__(128) void reduce_b_kernel(
    const float* __restrict__ blockSums, float* __restrict__ out) {
  float s = blockSums[threadIdx.x];
#pragma unroll
  for (int off = 32; off > 0; off >>= 1) s += __shfl_down(s, off, 64);
  __shared__ float part[2];
  int wid = threadIdx.x >> 6, lane = threadIdx.x & 63;
  if (lane == 0) part[wid] = s;
  __syncthreads();
  if (threadIdx.x == 0) out[0] = part[0] + part[1];
}

extern "C" void kernel_launch(void* const* d_in, const int* in_sizes, int n_in,
                              void* d_out, int out_size, void* d_ws,
                              size_t ws_size, hipStream_t stream) {
  const float* preds = (const float*)d_in[0];  // [B, M, 3]
  const float* gts = (const float*)d_in[1];    // [B, N, 3]

  // ws layout: partial [2][SPLIT][PER_DIR] f32 (4 MB) | blockSums[128] f32 |
  //            Tp [PER_DIR] f4 (1 MB) | Tg [PER_DIR] f4 (1 MB)
  float* partial = (float*)d_ws;
  float* blockSums = partial + (size_t)2 * SPLIT * PER_DIR;
  float4* Tp = (float4*)(blockSums + 128);
  float4* Tg = Tp + PER_DIR;

  transform_kernel<<<2 * PER_DIR / 256, 256, 0, stream>>>(preds, gts, Tp, Tg);

  const int ownChunks = NPTS / (256 * U);  // 4
  chamfer_min_kernel<<<2 * BATCH * ownChunks * SPLIT, 256, 0, stream>>>(
      Tg, Tp, partial, partial + (size_t)SPLIT * PER_DIR);

  reduce_a_kernel<<<128, 256, 0, stream>>>(partial, blockSums);
  reduce_b_kernel<<<1, 128, 0, stream>>>(blockSums, (float*)d_out);
}

// Round 5
// 90.362 us; speedup vs baseline: 1.4039x; 1.4039x over previous
//
#include <hip/hip_runtime.h>

// Chamfer loss, B=8, N=M=8192, D=3, fp32.
// d(p,s) = ||s||^2 - 2 p.s + ||p||^2. Scan points staged in LDS as
// (-2x,-2y,-2z,||x||^2) (transformed in-kernel); own points raw in VGPRs.
// Inner pair = 3 FMA; pairs merged with min3. Own norm added after the min.
// partial[dir][SPLIT][B*8192] written non-atomically; reduce = min over SPLIT + sum.

#define U 8
#define NPTS 8192      // N == M
#define BATCH 8
#define PER_DIR (BATCH * NPTS)  // 65536 owned slots per direction

template <int SPLIT>
__global__ __launch_bounds__(256, 4) void chamfer_min_kernel(
    const float* __restrict__ preds, const float* __restrict__ gts,
    float* __restrict__ partial) {
  constexpr int scanLen = NPTS / SPLIT;
  __shared__ float4 sTile[scanLen];
  const int tid = threadIdx.x;
  const int ownPerBlock = 256 * U;              // 2048
  const int ownChunks = NPTS / ownPerBlock;     // 4
  const int blocksPerDir = BATCH * ownChunks * SPLIT;

  int id = blockIdx.x;
  const int dir = id / blocksPerDir;
  id %= blocksPerDir;
  const int b = id / (ownChunks * SPLIT);
  const int r = id % (ownChunks * SPLIT);
  const int oc = r / SPLIT;
  const int sp = r % SPLIT;

  const float* ownRaw =
      (dir == 0 ? preds : gts) + ((size_t)b * NPTS + oc * ownPerBlock) * 3;
  const float* scanRaw =
      (dir == 0 ? gts : preds) + ((size_t)b * NPTS + sp * scanLen) * 3;

  // stage transformed scan slice into LDS (once per block)
  for (int i = tid; i < scanLen; i += 256) {
    float x = scanRaw[3 * i], y = scanRaw[3 * i + 1], z = scanRaw[3 * i + 2];
    sTile[i] = make_float4(-2.0f * x, -2.0f * y, -2.0f * z,
                           fmaf(x, x, fmaf(y, y, z * z)));
  }

  float px[U], py[U], pz[U], pw[U], m[U];
#pragma unroll
  for (int k = 0; k < U; ++k) {
    int j = k * 256 + tid;
    float x = ownRaw[3 * j], y = ownRaw[3 * j + 1], z = ownRaw[3 * j + 2];
    px[k] = x; py[k] = y; pz[k] = z;
    pw[k] = fmaf(x, x, fmaf(y, y, z * z));  // ||p||^2, added after the min
    m[k] = 3.0e38f;
  }
  __syncthreads();

#pragma unroll 4
  for (int t = 0; t < scanLen; t += 2) {
    float4 s0 = sTile[t];
    float4 s1 = sTile[t + 1];
#pragma unroll
    for (int k = 0; k < U; ++k) {
      float v0 = fmaf(px[k], s0.x, fmaf(py[k], s0.y, fmaf(pz[k], s0.z, s0.w)));
      float v1 = fmaf(px[k], s1.x, fmaf(py[k], s1.y, fmaf(pz[k], s1.z, s1.w)));
      m[k] = fminf(fminf(m[k], v0), v1);  // v_min3_f32
    }
  }

  float* outp = partial + ((size_t)dir * SPLIT + sp) * PER_DIR +
                (size_t)b * NPTS + oc * ownPerBlock;
#pragma unroll
  for (int k = 0; k < U; ++k) {
    outp[k * 256 + tid] = m[k] + pw[k];
  }
}

// Stage A: min over SPLIT partials per owned slot, sum per block.
template <int SPLIT>
__global__ __launch_bounds__(256) void reduce_a_kernel(
    const float* __restrict__ partial, float* __restrict__ blockSums) {
  const int nSlots = 2 * PER_DIR;  // 131072
  const int gid = blockIdx.x * 256 + threadIdx.x;
  const int stride = 128 * 256;
  float s = 0.0f;
  for (int sl = gid; sl < nSlots; sl += stride) {
    const int dir = sl >> 16;          // PER_DIR == 65536
    const int idx = sl & (PER_DIR - 1);
    const float* base = partial + (size_t)dir * SPLIT * PER_DIR + idx;
    float mn = base[0];
#pragma unroll
    for (int sp = 1; sp < SPLIT; ++sp)
      mn = fminf(mn, base[(size_t)sp * PER_DIR]);
    s += mn;
  }
#pragma unroll
  for (int off = 32; off > 0; off >>= 1) s += __shfl_down(s, off, 64);
  __shared__ float part[4];
  int wid = threadIdx.x >> 6, lane = threadIdx.x & 63;
  if (lane == 0) part[wid] = s;
  __syncthreads();
  if (threadIdx.x == 0) {
    blockSums[blockIdx.x] = part[0] + part[1] + part[2] + part[3];
  }
}

__global__ __launch_bounds__(128) void reduce_b_kernel(
    const float* __restrict__ blockSums, float* __restrict__ out) {
  float s = blockSums[threadIdx.x];
#pragma unroll
  for (int off = 32; off > 0; off >>= 1) s += __shfl_down(s, off, 64);
  __shared__ float part[2];
  int wid = threadIdx.x >> 6, lane = threadIdx.x & 63;
  if (lane == 0) part[wid] = s;
  __syncthreads();
  if (threadIdx.x == 0) out[0] = part[0] + part[1];
}

extern "C" void kernel_launch(void* const* d_in, const int* in_sizes, int n_in,
                              void* d_out, int out_size, void* d_ws,
                              size_t ws_size, hipStream_t stream) {
  const float* preds = (const float*)d_in[0];  // [B, M, 3]
  const float* gts = (const float*)d_in[1];    // [B, N, 3]

  float* partial = (float*)d_ws;
  const int ownChunks = NPTS / (256 * U);  // 4

  // SPLIT=16 needs 2*16*PER_DIR + 128 floats of ws; fall back to 8 if short.
  const size_t need16 = ((size_t)2 * 16 * PER_DIR + 128) * sizeof(float);
  if (ws_size >= need16) {
    constexpr int SPLIT = 16;
    float* blockSums = partial + (size_t)2 * SPLIT * PER_DIR;
    chamfer_min_kernel<SPLIT>
        <<<2 * BATCH * ownChunks * SPLIT, 256, 0, stream>>>(preds, gts, partial);
    reduce_a_kernel<SPLIT><<<128, 256, 0, stream>>>(partial, blockSums);
    reduce_b_kernel<<<1, 128, 0, stream>>>(blockSums, (float*)d_out);
  } else {
    constexpr int SPLIT = 8;
    float* blockSums = partial + (size_t)2 * SPLIT * PER_DIR;
    chamfer_min_kernel<SPLIT>
        <<<2 * BATCH * ownChunks * SPLIT, 256, 0, stream>>>(preds, gts, partial);
    reduce_a_kernel<SPLIT><<<128, 256, 0, stream>>>(partial, blockSums);
    reduce_b_kernel<<<1, 128, 0, stream>>>(blockSums, (float*)d_out);
  }
}

// Round 6
// 87.852 us; speedup vs baseline: 1.4440x; 1.0286x over previous
//
#include <hip/hip_runtime.h>

// Chamfer loss, B=8, N=M=8192, D=3, fp32.
// v = ||s||^2 - 2 p.s computed for TWO scan points per v_pk_fma_f32:
//   LDS tile is pair-transposed: per scan pair j -> {-2x0,-2x1,-2y0,-2y1},
//   {-2z0,-2z1,|s0|^2,|s1|^2}. Own coords dup'd into float2s.
//   per (own k, scan pair): 3 pk_fma + 1 min3  = 2.0 instr/pair.
// min over s, then + ||p||^2 after the min.

typedef __attribute__((ext_vector_type(2))) float f2;

#define U 8
#define NPTS 8192      // N == M
#define BATCH 8
#define PER_DIR (BATCH * NPTS)  // 65536 owned slots per direction

__device__ __forceinline__ f2 pk_fma(f2 a, f2 b, f2 c) {
  f2 d;
  asm("v_pk_fma_f32 %0, %1, %2, %3" : "=v"(d) : "v"(a), "v"(b), "v"(c));
  return d;
}

template <int SPLIT>
__global__ __launch_bounds__(256, 4) void chamfer_min_kernel(
    const float* __restrict__ preds, const float* __restrict__ gts,
    float* __restrict__ partial) {
  constexpr int scanLen = NPTS / SPLIT;
  constexpr int nPairs = scanLen / 2;
  __shared__ float4 sTile[nPairs * 2];
  const int tid = threadIdx.x;
  const int ownPerBlock = 256 * U;              // 2048
  const int ownChunks = NPTS / ownPerBlock;     // 4
  const int blocksPerDir = BATCH * ownChunks * SPLIT;

  int id = blockIdx.x;
  const int dir = id / blocksPerDir;
  id %= blocksPerDir;
  const int b = id / (ownChunks * SPLIT);
  const int r = id % (ownChunks * SPLIT);
  const int oc = r / SPLIT;
  const int sp = r % SPLIT;

  const float* ownRaw =
      (dir == 0 ? preds : gts) + ((size_t)b * NPTS + oc * ownPerBlock) * 3;
  const float* scanRaw =
      (dir == 0 ? gts : preds) + ((size_t)b * NPTS + sp * scanLen) * 3;

  // stage pair-transposed scan tile (one pair per thread)
  for (int j = tid; j < nPairs; j += 256) {
    float x0 = scanRaw[6 * j + 0], y0 = scanRaw[6 * j + 1],
          z0 = scanRaw[6 * j + 2];
    float x1 = scanRaw[6 * j + 3], y1 = scanRaw[6 * j + 4],
          z1 = scanRaw[6 * j + 5];
    sTile[2 * j] = make_float4(-2.0f * x0, -2.0f * x1, -2.0f * y0, -2.0f * y1);
    sTile[2 * j + 1] =
        make_float4(-2.0f * z0, -2.0f * z1, fmaf(x0, x0, fmaf(y0, y0, z0 * z0)),
                    fmaf(x1, x1, fmaf(y1, y1, z1 * z1)));
  }

  f2 pxp[U], pyp[U], pzp[U];
  float pw[U], m[U];
#pragma unroll
  for (int k = 0; k < U; ++k) {
    int j = k * 256 + tid;
    float x = ownRaw[3 * j], y = ownRaw[3 * j + 1], z = ownRaw[3 * j + 2];
    pxp[k] = (f2){x, x};
    pyp[k] = (f2){y, y};
    pzp[k] = (f2){z, z};
    pw[k] = fmaf(x, x, fmaf(y, y, z * z));  // ||p||^2, added after the min
    m[k] = 3.0e38f;
  }
  __syncthreads();

#pragma unroll 2
  for (int j = 0; j < nPairs; ++j) {
    float4 A = sTile[2 * j];      // {-2x0,-2x1,-2y0,-2y1}
    float4 Bq = sTile[2 * j + 1]; // {-2z0,-2z1,w0,w1}
    f2 sx = (f2){A.x, A.y};
    f2 sy = (f2){A.z, A.w};
    f2 sz = (f2){Bq.x, Bq.y};
    f2 sw = (f2){Bq.z, Bq.w};
#pragma unroll
    for (int k = 0; k < U; ++k) {
      f2 acc = pk_fma(pzp[k], sz, sw);
      acc = pk_fma(pyp[k], sy, acc);
      acc = pk_fma(pxp[k], sx, acc);   // acc = {d(p,s0), d(p,s1)} - ||p||^2
      m[k] = fminf(fminf(m[k], acc.x), acc.y);  // v_min3_f32
    }
  }

  float* outp = partial + ((size_t)dir * SPLIT + sp) * PER_DIR +
                (size_t)b * NPTS + oc * ownPerBlock;
#pragma unroll
  for (int k = 0; k < U; ++k) {
    outp[k * 256 + tid] = m[k] + pw[k];
  }
}

// Stage A: min over SPLIT partials per owned slot, sum per block.
template <int SPLIT>
__global__ __launch_bounds__(256) void reduce_a_kernel(
    const float* __restrict__ partial, float* __restrict__ blockSums) {
  const int nSlots = 2 * PER_DIR;  // 131072
  const int gid = blockIdx.x * 256 + threadIdx.x;
  const int stride = 128 * 256;
  float s = 0.0f;
  for (int sl = gid; sl < nSlots; sl += stride) {
    const int dir = sl >> 16;          // PER_DIR == 65536
    const int idx = sl & (PER_DIR - 1);
    const float* base = partial + (size_t)dir * SPLIT * PER_DIR + idx;
    float mn = base[0];
#pragma unroll
    for (int sp = 1; sp < SPLIT; ++sp)
      mn = fminf(mn, base[(size_t)sp * PER_DIR]);
    s += mn;
  }
#pragma unroll
  for (int off = 32; off > 0; off >>= 1) s += __shfl_down(s, off, 64);
  __shared__ float part[4];
  int wid = threadIdx.x >> 6, lane = threadIdx.x & 63;
  if (lane == 0) part[wid] = s;
  __syncthreads();
  if (threadIdx.x == 0) {
    blockSums[blockIdx.x] = part[0] + part[1] + part[2] + part[3];
  }
}

__global__ __launch_bounds__(128) void reduce_b_kernel(
    const float* __restrict__ blockSums, float* __restrict__ out) {
  float s = blockSums[threadIdx.x];
#pragma unroll
  for (int off = 32; off > 0; off >>= 1) s += __shfl_down(s, off, 64);
  __shared__ float part[2];
  int wid = threadIdx.x >> 6, lane = threadIdx.x & 63;
  if (lane == 0) part[wid] = s;
  __syncthreads();
  if (threadIdx.x == 0) out[0] = part[0] + part[1];
}

extern "C" void kernel_launch(void* const* d_in, const int* in_sizes, int n_in,
                              void* d_out, int out_size, void* d_ws,
                              size_t ws_size, hipStream_t stream) {
  const float* preds = (const float*)d_in[0];  // [B, M, 3]
  const float* gts = (const float*)d_in[1];    // [B, N, 3]

  float* partial = (float*)d_ws;
  const int ownChunks = NPTS / (256 * U);  // 4

  const size_t need16 = ((size_t)2 * 16 * PER_DIR + 128) * sizeof(float);
  if (ws_size >= need16) {
    constexpr int SPLIT = 16;
    float* blockSums = partial + (size_t)2 * SPLIT * PER_DIR;
    chamfer_min_kernel<SPLIT>
        <<<2 * BATCH * ownChunks * SPLIT, 256, 0, stream>>>(preds, gts, partial);
    reduce_a_kernel<SPLIT><<<128, 256, 0, stream>>>(partial, blockSums);
    reduce_b_kernel<<<1, 128, 0, stream>>>(blockSums, (float*)d_out);
  } else {
    constexpr int SPLIT = 8;
    float* blockSums = partial + (size_t)2 * SPLIT * PER_DIR;
    chamfer_min_kernel<SPLIT>
        <<<2 * BATCH * ownChunks * SPLIT, 256, 0, stream>>>(preds, gts, partial);
    reduce_a_kernel<SPLIT><<<128, 256, 0, stream>>>(partial, blockSums);
    reduce_b_kernel<<<1, 128, 0, stream>>>(blockSums, (float*)d_out);
  }
}

// Round 7
// 60.495 us; speedup vs baseline: 2.0970x; 1.4522x over previous
//
#include <hip/hip_runtime.h>

// Chamfer loss via MFMA, B=8, N=M=8192, D=3, fp32.
// D[i][j] = ||p_i||^2 + ||s_j||^2 - 2 p_i.s_j computed by ONE
// v_mfma_f32_32x32x16_bf16 per 32x32 pair-tile using a bf16 hi/lo split:
//  A k-slots (per own row, -2p folded): [ahx,ahy,ahz, ahx,ahy,ahz, alx,aly |
//                                        alz, alx,aly,alz, 1,1, wph,wpl]
//  B k-slots (per scan col):            [bhx,bhy,bhz, blx,bly,blz, bhx,bhy |
//                                        bhz, blx,bly,blz, wsh,wsl, 1,1]
//  sum_k A[k]B[k] = (ah+al).(bh+bl) + ws + wp  (exact to ~2^-18 rel).
// Sum over rows of min over cols is invariant to row/col permutations, so
// only the k-slot agreement between A and B layouts is correctness-critical.

typedef __attribute__((ext_vector_type(8))) short short8;
typedef __attribute__((ext_vector_type(16))) float f32x16;
typedef unsigned int uint32;
typedef unsigned short ushort16_t;

#define NPTS 8192
#define BATCH 8
#define PER_DIR (BATCH * NPTS)  // 65536

__device__ __forceinline__ unsigned short f2bf(float f) {
  uint32 u = __float_as_uint(f);
  return (unsigned short)((u + 0x7FFFu + ((u >> 16) & 1u)) >> 16);  // RNE
}
__device__ __forceinline__ float bf2f(unsigned short h) {
  return __uint_as_float(((uint32)h) << 16);
}

// Pack every point of both clouds into its 16-slot B-row (32 B/point).
__global__ __launch_bounds__(256) void pack_kernel(
    const float* __restrict__ preds, const float* __restrict__ gts,
    unsigned short* __restrict__ Bp, unsigned short* __restrict__ Bg) {
  int i = blockIdx.x * 256 + threadIdx.x;  // 0 .. 2*PER_DIR-1
  const float* src;
  unsigned short* dst;
  int j;
  if (i < PER_DIR) { src = gts;   dst = Bg; j = i; }
  else             { src = preds; dst = Bp; j = i - PER_DIR; }
  float x = src[3 * j], y = src[3 * j + 1], z = src[3 * j + 2];
  float ws = fmaf(x, x, fmaf(y, y, z * z));
  unsigned short bhx = f2bf(x), bhy = f2bf(y), bhz = f2bf(z);
  unsigned short blx = f2bf(x - bf2f(bhx));
  unsigned short bly = f2bf(y - bf2f(bhy));
  unsigned short blz = f2bf(z - bf2f(bhz));
  unsigned short wsh = f2bf(ws);
  unsigned short wsl = f2bf(ws - bf2f(wsh));
  const unsigned short one = 0x3F80;
  uint4 w0, w1;
  w0.x = (uint32)bhx | ((uint32)bhy << 16);
  w0.y = (uint32)bhz | ((uint32)blx << 16);
  w0.z = (uint32)bly | ((uint32)blz << 16);
  w0.w = (uint32)bhx | ((uint32)bhy << 16);
  w1.x = (uint32)bhz | ((uint32)blx << 16);
  w1.y = (uint32)bly | ((uint32)blz << 16);
  w1.z = (uint32)wsh | ((uint32)wsl << 16);
  w1.w = (uint32)one | ((uint32)one << 16);
  uint4* d4 = (uint4*)(dst + (size_t)j * 16);
  d4[0] = w0;
  d4[1] = w1;
}

// 256 blocks (1/CU): dir(2) x batch(8) x oc(16). 512 thr = 8 waves.
// Wave w owns rows w*64 + [0..63] of its 512-own chunk (2 A-frags of 32 rows).
// Scans all 8192 packed B rows in 32-col tiles: 2 MFMA/frag per 2 tiles + min3.
__global__ __launch_bounds__(512, 2) void chamfer_mfma_kernel(
    const float* __restrict__ preds, const float* __restrict__ gts,
    const unsigned short* __restrict__ Bp, const unsigned short* __restrict__ Bg,
    float* __restrict__ partials) {
  const int tid = threadIdx.x;
  const int lane = tid & 63;
  const int wid = tid >> 6;      // 0..7
  const int half = lane >> 5;    // k-group: 0 -> k0-7, 1 -> k8-15
  const int lr = lane & 31;      // row (A) / col (B) slot

  int id = blockIdx.x;
  const int dir = id >> 7;
  id &= 127;
  const int b = id >> 4;
  const int oc = id & 15;

  const float* own =
      (dir == 0 ? preds : gts) + ((size_t)b * NPTS + oc * 512) * 3;
  const unsigned short* Bsc =
      (dir == 0 ? Bg : Bp) + (size_t)b * NPTS * 16;

  // Build the two A fragments (rows wid*64+lr and wid*64+32+lr).
  short8 A[2];
#pragma unroll
  for (int f = 0; f < 2; ++f) {
    int row = wid * 64 + f * 32 + lr;
    float x = own[3 * row], y = own[3 * row + 1], z = own[3 * row + 2];
    float ax = -2.0f * x, ay = -2.0f * y, az = -2.0f * z;
    unsigned short ahx = f2bf(ax), ahy = f2bf(ay), ahz = f2bf(az);
    unsigned short alx = f2bf(ax - bf2f(ahx));
    unsigned short aly = f2bf(ay - bf2f(ahy));
    unsigned short alz = f2bf(az - bf2f(ahz));
    float wp = fmaf(x, x, fmaf(y, y, z * z));
    unsigned short wph = f2bf(wp);
    unsigned short wpl = f2bf(wp - bf2f(wph));
    const unsigned short one = 0x3F80;
    unsigned short e0, e1, e2, e3, e4, e5, e6, e7;
    if (half == 0) {
      e0 = ahx; e1 = ahy; e2 = ahz; e3 = ahx;
      e4 = ahy; e5 = ahz; e6 = alx; e7 = aly;
    } else {
      e0 = alz; e1 = alx; e2 = aly; e3 = alz;
      e4 = one; e5 = one; e6 = wph; e7 = wpl;
    }
    short8 a;
    a[0] = (short)e0; a[1] = (short)e1; a[2] = (short)e2; a[3] = (short)e3;
    a[4] = (short)e4; a[5] = (short)e5; a[6] = (short)e6; a[7] = (short)e7;
    A[f] = a;
  }

  f32x16 zc, m0, m1;
#pragma unroll
  for (int r = 0; r < 16; ++r) { zc[r] = 0.0f; m0[r] = 3.0e38f; m1[r] = 3.0e38f; }

  // B fragment address: tile t, lane -> 16B chunk index t*64 + lr*2 + half.
  const short8* Bv = (const short8*)Bsc;
  const int boff = lr * 2 + half;

#pragma unroll 2
  for (int t = 0; t < NPTS / 32; t += 2) {
    short8 b0 = Bv[(size_t)t * 64 + boff];
    short8 b1 = Bv[(size_t)(t + 1) * 64 + boff];
    f32x16 D00 = __builtin_amdgcn_mfma_f32_32x32x16_bf16(A[0], b0, zc, 0, 0, 0);
    f32x16 D10 = __builtin_amdgcn_mfma_f32_32x32x16_bf16(A[1], b0, zc, 0, 0, 0);
    f32x16 D01 = __builtin_amdgcn_mfma_f32_32x32x16_bf16(A[0], b1, zc, 0, 0, 0);
    f32x16 D11 = __builtin_amdgcn_mfma_f32_32x32x16_bf16(A[1], b1, zc, 0, 0, 0);
#pragma unroll
    for (int r = 0; r < 16; ++r) {
      m0[r] = fminf(fminf(m0[r], D00[r]), D01[r]);  // v_min3_f32
      m1[r] = fminf(fminf(m1[r], D10[r]), D11[r]);
    }
  }

  // Per-reg: min over the 32 col-slots (lanes within each half).
#pragma unroll
  for (int off = 1; off < 32; off <<= 1) {
#pragma unroll
    for (int r = 0; r < 16; ++r) {
      m0[r] = fminf(m0[r], __shfl_xor(m0[r], off, 64));
      m1[r] = fminf(m1[r], __shfl_xor(m1[r], off, 64));
    }
  }
  // Each half's lanes now all hold its 16+16 row-mins; sum them.
  float s = 0.0f;
#pragma unroll
  for (int r = 0; r < 16; ++r) s += m0[r] + m1[r];

  __shared__ float acc[16];
  if (lr == 0) acc[wid * 2 + half] = s;  // lanes 0 and 32 of each wave
  __syncthreads();
  if (tid == 0) {
    float tot = 0.0f;
#pragma unroll
    for (int i2 = 0; i2 < 16; ++i2) tot += acc[i2];
    partials[blockIdx.x] = tot;
  }
}

__global__ __launch_bounds__(256) void reduce_kernel(
    const float* __restrict__ partials, float* __restrict__ out) {
  float s = partials[threadIdx.x];
#pragma unroll
  for (int off = 32; off > 0; off >>= 1) s += __shfl_down(s, off, 64);
  __shared__ float p[4];
  int wid = threadIdx.x >> 6, lane = threadIdx.x & 63;
  if (lane == 0) p[wid] = s;
  __syncthreads();
  if (threadIdx.x == 0) out[0] = p[0] + p[1] + p[2] + p[3];
}

extern "C" void kernel_launch(void* const* d_in, const int* in_sizes, int n_in,
                              void* d_out, int out_size, void* d_ws,
                              size_t ws_size, hipStream_t stream) {
  const float* preds = (const float*)d_in[0];  // [B, M, 3]
  const float* gts = (const float*)d_in[1];    // [B, N, 3]

  // ws: Bp [PER_DIR*16] u16 (2MB) | Bg [PER_DIR*16] u16 (2MB) | partials[256]
  unsigned short* Bp = (unsigned short*)d_ws;
  unsigned short* Bg = Bp + (size_t)PER_DIR * 16;
  float* partials = (float*)(Bg + (size_t)PER_DIR * 16);

  pack_kernel<<<2 * PER_DIR / 256, 256, 0, stream>>>(preds, gts, Bp, Bg);
  chamfer_mfma_kernel<<<256, 512, 0, stream>>>(preds, gts, Bp, Bg, partials);
  reduce_kernel<<<1, 256, 0, stream>>>(partials, (float*)d_out);
}

// Round 8
// 53.364 us; speedup vs baseline: 2.3772x; 1.1336x over previous
//
#include <hip/hip_runtime.h>

// Chamfer loss via MFMA, B=8, N=M=8192, D=3, fp32.
// D[i][j] = ||p_i||^2 + ||s_j||^2 - 2 p_i.s_j via one mfma_f32_32x32x16_bf16
// per 32x32 pair-tile with bf16 hi/lo split (exact to ~2^-18 rel):
//  A k-slots (own row, -2p folded): [ahx,ahy,ahz,ahx,ahy,ahz,alx,aly |
//                                    alz,alx,aly,alz, 1,1, wph,wpl]
//  B k-slots (scan col):            [bhx,bhy,bhz,blx,bly,blz,bhx,bhy |
//                                    bhz,blx,bly,blz, wsh,wsl, 1,1]
// Scan dim split by SSPLIT for occupancy; per-row partial mins -> ws;
// reduce = min over SSPLIT + sum.

typedef __attribute__((ext_vector_type(8))) short short8;
typedef __attribute__((ext_vector_type(16))) float f32x16;
typedef unsigned int uint32;

#define NPTS 8192
#define BATCH 8
#define PER_DIR (BATCH * NPTS)  // 65536 rows per direction
#define SSPLIT 2

__device__ __forceinline__ unsigned short f2bf(float f) {
  uint32 u = __float_as_uint(f);
  return (unsigned short)((u + 0x7FFFu + ((u >> 16) & 1u)) >> 16);  // RNE
}
__device__ __forceinline__ float bf2f(unsigned short h) {
  return __uint_as_float(((uint32)h) << 16);
}

// Pack every point of both clouds into its 16-slot B-row (32 B/point).
__global__ __launch_bounds__(256) void pack_kernel(
    const float* __restrict__ preds, const float* __restrict__ gts,
    unsigned short* __restrict__ Bp, unsigned short* __restrict__ Bg) {
  int i = blockIdx.x * 256 + threadIdx.x;  // 0 .. 2*PER_DIR-1
  const float* src;
  unsigned short* dst;
  int j;
  if (i < PER_DIR) { src = gts;   dst = Bg; j = i; }
  else             { src = preds; dst = Bp; j = i - PER_DIR; }
  float x = src[3 * j], y = src[3 * j + 1], z = src[3 * j + 2];
  float ws = fmaf(x, x, fmaf(y, y, z * z));
  unsigned short bhx = f2bf(x), bhy = f2bf(y), bhz = f2bf(z);
  unsigned short blx = f2bf(x - bf2f(bhx));
  unsigned short bly = f2bf(y - bf2f(bhy));
  unsigned short blz = f2bf(z - bf2f(bhz));
  unsigned short wsh = f2bf(ws);
  unsigned short wsl = f2bf(ws - bf2f(wsh));
  const unsigned short one = 0x3F80;
  uint4 w0, w1;
  w0.x = (uint32)bhx | ((uint32)bhy << 16);
  w0.y = (uint32)bhz | ((uint32)blx << 16);
  w0.z = (uint32)bly | ((uint32)blz << 16);
  w0.w = (uint32)bhx | ((uint32)bhy << 16);
  w1.x = (uint32)bhz | ((uint32)blx << 16);
  w1.y = (uint32)bly | ((uint32)blz << 16);
  w1.z = (uint32)wsh | ((uint32)wsl << 16);
  w1.w = (uint32)one | ((uint32)one << 16);
  uint4* d4 = (uint4*)(dst + (size_t)j * 16);
  d4[0] = w0;
  d4[1] = w1;
}

// 512 blocks (2/CU): dir(2) x batch(8) x oc(16) x sp(SSPLIT).
// 512 thr = 8 waves; wave owns 64 rows (2 A-frags of 32 rows); scans its
// NPTS/SSPLIT B slice in 32-col tiles, 4 tiles per iteration.
__global__ __launch_bounds__(512, 4) void chamfer_mfma_kernel(
    const float* __restrict__ preds, const float* __restrict__ gts,
    const unsigned short* __restrict__ Bp, const unsigned short* __restrict__ Bg,
    float* __restrict__ partMins) {
  const int tid = threadIdx.x;
  const int lane = tid & 63;
  const int wid = tid >> 6;      // 0..7
  const int half = lane >> 5;    // k-group: 0 -> k0-7, 1 -> k8-15
  const int lr = lane & 31;      // row (A) / col (B) slot

  int id = blockIdx.x;
  const int dir = id >> 8;
  id &= 255;
  const int b = id >> 5;
  const int oc = (id >> 1) & 15;
  const int sp = id & 1;
  const int scanTiles = NPTS / SSPLIT / 32;  // 128

  const float* own =
      (dir == 0 ? preds : gts) + ((size_t)b * NPTS + oc * 512) * 3;
  const unsigned short* Bsc = (dir == 0 ? Bg : Bp) +
                              ((size_t)b * NPTS + sp * (NPTS / SSPLIT)) * 16;

  // Build the two A fragments (rows wid*64+lr and wid*64+32+lr).
  short8 A[2];
#pragma unroll
  for (int f = 0; f < 2; ++f) {
    int row = wid * 64 + f * 32 + lr;
    float x = own[3 * row], y = own[3 * row + 1], z = own[3 * row + 2];
    float ax = -2.0f * x, ay = -2.0f * y, az = -2.0f * z;
    unsigned short ahx = f2bf(ax), ahy = f2bf(ay), ahz = f2bf(az);
    unsigned short alx = f2bf(ax - bf2f(ahx));
    unsigned short aly = f2bf(ay - bf2f(ahy));
    unsigned short alz = f2bf(az - bf2f(ahz));
    float wp = fmaf(x, x, fmaf(y, y, z * z));
    unsigned short wph = f2bf(wp);
    unsigned short wpl = f2bf(wp - bf2f(wph));
    const unsigned short one = 0x3F80;
    unsigned short e0, e1, e2, e3, e4, e5, e6, e7;
    if (half == 0) {
      e0 = ahx; e1 = ahy; e2 = ahz; e3 = ahx;
      e4 = ahy; e5 = ahz; e6 = alx; e7 = aly;
    } else {
      e0 = alz; e1 = alx; e2 = aly; e3 = alz;
      e4 = one; e5 = one; e6 = wph; e7 = wpl;
    }
    short8 a;
    a[0] = (short)e0; a[1] = (short)e1; a[2] = (short)e2; a[3] = (short)e3;
    a[4] = (short)e4; a[5] = (short)e5; a[6] = (short)e6; a[7] = (short)e7;
    A[f] = a;
  }

  f32x16 zc, m0, m1;
#pragma unroll
  for (int r = 0; r < 16; ++r) { zc[r] = 0.0f; m0[r] = 3.0e38f; m1[r] = 3.0e38f; }

  const short8* Bv = (const short8*)Bsc;
  const int boff = lr * 2 + half;

  for (int t = 0; t < scanTiles; t += 4) {
    short8 b0 = Bv[(size_t)t * 64 + boff];
    short8 b1 = Bv[(size_t)(t + 1) * 64 + boff];
    short8 b2 = Bv[(size_t)(t + 2) * 64 + boff];
    short8 b3 = Bv[(size_t)(t + 3) * 64 + boff];
    f32x16 D00 = __builtin_amdgcn_mfma_f32_32x32x16_bf16(A[0], b0, zc, 0, 0, 0);
    f32x16 D10 = __builtin_amdgcn_mfma_f32_32x32x16_bf16(A[1], b0, zc, 0, 0, 0);
    f32x16 D01 = __builtin_amdgcn_mfma_f32_32x32x16_bf16(A[0], b1, zc, 0, 0, 0);
    f32x16 D11 = __builtin_amdgcn_mfma_f32_32x32x16_bf16(A[1], b1, zc, 0, 0, 0);
    f32x16 D02 = __builtin_amdgcn_mfma_f32_32x32x16_bf16(A[0], b2, zc, 0, 0, 0);
    f32x16 D12 = __builtin_amdgcn_mfma_f32_32x32x16_bf16(A[1], b2, zc, 0, 0, 0);
    f32x16 D03 = __builtin_amdgcn_mfma_f32_32x32x16_bf16(A[0], b3, zc, 0, 0, 0);
    f32x16 D13 = __builtin_amdgcn_mfma_f32_32x32x16_bf16(A[1], b3, zc, 0, 0, 0);
#pragma unroll
    for (int r = 0; r < 16; ++r) {
      m0[r] = fminf(fminf(m0[r], D00[r]), D01[r]);  // v_min3_f32
      m0[r] = fminf(fminf(m0[r], D02[r]), D03[r]);
      m1[r] = fminf(fminf(m1[r], D10[r]), D11[r]);
      m1[r] = fminf(fminf(m1[r], D12[r]), D13[r]);
    }
  }

  // Min over the 32 col-slots (butterfly within each 32-lane group).
#pragma unroll
  for (int off = 1; off < 32; off <<= 1) {
#pragma unroll
    for (int r = 0; r < 16; ++r) {
      m0[r] = fminf(m0[r], __shfl_xor(m0[r], off, 64));
      m1[r] = fminf(m1[r], __shfl_xor(m1[r], off, 64));
    }
  }

  // Store per-row partial mins (rows distinct & bijective over (r,half)).
  float* outp = partMins + ((size_t)dir * SSPLIT + sp) * PER_DIR +
                (size_t)b * NPTS + oc * 512 + wid * 64;
  if (lr == 0) {
#pragma unroll
    for (int r = 0; r < 16; ++r) {
      int rowid = (r & 3) + 8 * (r >> 2) + 4 * half;
      outp[rowid] = m0[r];
      outp[32 + rowid] = m1[r];
    }
  }
}

// Min over SSPLIT partials per row, sum per block. partMins: [2][SSPLIT][PER_DIR].
__global__ __launch_bounds__(256) void reduce_a_kernel(
    const float* __restrict__ partMins, float* __restrict__ blockSums) {
  const int nSlots = 2 * PER_DIR;  // 131072
  const int gid = blockIdx.x * 256 + threadIdx.x;
  const int stride = 128 * 256;
  float s = 0.0f;
  for (int sl = gid; sl < nSlots; sl += stride) {
    const int dir = sl >> 16;          // PER_DIR == 65536
    const int idx = sl & (PER_DIR - 1);
    const float* base = partMins + (size_t)dir * SSPLIT * PER_DIR + idx;
    float mn = base[0];
#pragma unroll
    for (int sp = 1; sp < SSPLIT; ++sp)
      mn = fminf(mn, base[(size_t)sp * PER_DIR]);
    s += mn;
  }
#pragma unroll
  for (int off = 32; off > 0; off >>= 1) s += __shfl_down(s, off, 64);
  __shared__ float part[4];
  int wid = threadIdx.x >> 6, lane = threadIdx.x & 63;
  if (lane == 0) part[wid] = s;
  __syncthreads();
  if (threadIdx.x == 0)
    blockSums[blockIdx.x] = part[0] + part[1] + part[2] + part[3];
}

__global__ __launch_bounds__(128) void reduce_b_kernel(
    const float* __restrict__ blockSums, float* __restrict__ out) {
  float s = blockSums[threadIdx.x];
#pragma unroll
  for (int off = 32; off > 0; off >>= 1) s += __shfl_down(s, off, 64);
  __shared__ float part[2];
  int wid = threadIdx.x >> 6, lane = threadIdx.x & 63;
  if (lane == 0) part[wid] = s;
  __syncthreads();
  if (threadIdx.x == 0) out[0] = part[0] + part[1];
}

extern "C" void kernel_launch(void* const* d_in, const int* in_sizes, int n_in,
                              void* d_out, int out_size, void* d_ws,
                              size_t ws_size, hipStream_t stream) {
  const float* preds = (const float*)d_in[0];  // [B, M, 3]
  const float* gts = (const float*)d_in[1];    // [B, N, 3]

  // ws: Bp (2MB) | Bg (2MB) | partMins [2][SSPLIT][PER_DIR] (1MB) | blockSums
  unsigned short* Bp = (unsigned short*)d_ws;
  unsigned short* Bg = Bp + (size_t)PER_DIR * 16;
  float* partMins = (float*)(Bg + (size_t)PER_DIR * 16);
  float* blockSums = partMins + (size_t)2 * SSPLIT * PER_DIR;

  pack_kernel<<<2 * PER_DIR / 256, 256, 0, stream>>>(preds, gts, Bp, Bg);
  chamfer_mfma_kernel<<<2 * BATCH * 16 * SSPLIT, 512, 0, stream>>>(
      preds, gts, Bp, Bg, partMins);
  reduce_a_kernel<<<128, 256, 0, stream>>>(partMins, blockSums);
  reduce_b_kernel<<<1, 128, 0, stream>>>(blockSums, (float*)d_out);
}